// Round 3
// baseline (263.443 us; speedup 1.0000x reference)
//
#include <hip/hip_runtime.h>
#include <hip/hip_bf16.h>

using bf16 = __hip_bfloat16;
typedef __attribute__((ext_vector_type(4))) float  f32x4;
typedef __attribute__((ext_vector_type(8))) short  s16x8;

#define QSTRIDE 1040   // 128*8 + 16 pad (bf16 elems per k-quad block)
#define ASTRIDE 520    // 64*8 + 8 pad   (gemm_ln A tile)
#define BSTRIDE 2064   // 256*8 + 16 pad (gemm_ln B tile)
#define CMAX 256
#define RMAX 128
#define CSTRIDE 16     // col_cnt padding: one counter per 64B cache line

// wcat element offsets (all 8-elem aligned)
#define O_MW0  0        // mega W0 [1024,256]: node_w | Wk1@nw | Wv1@nw | Wq2@nw
#define O_MB0  262144   // mega b0 [1024]
#define O_MW1  263168   // mega W1 [512,256]: edge_w | Wq1@ew
#define O_MB1  394240   // mega b1 [512]
#define O_KV2W 394752   // e2n Wk,Wv [512,256]
#define O_KV2B 525824   // e2n bk,bv [512]
#define O_O1W  526336   // n2e_out_w [256,256]
#define O_O2W  591872   // e2n_out_w [256,256]
// total 657408 elems

// ---------------------------------------------------------------------------
// Fused front kernel. Blocks [0,128): combined-weight products
// C = attnW @ projW (bf16 out) + combined bias b' = ab + attnW@pb.
// Blocks [128,256): straight fp32->bf16 weight conversion segments.
// Blocks [256,2304): row lists via wave-per-row ballot compaction
// (no atomics/barriers/LDS) + col_cnt zero-fill.
// ---------------------------------------------------------------------------
struct PrepDesc {
    const float* aw[4]; const float* pw[4];
    const float* ab[4]; const float* pb[4];
    int cdst[4]; int bdst[4];
    const float* csrc[8]; int coff[8]; int ccnt[8];
};

__global__ __launch_bounds__(256)
void prep_front(PrepDesc d, bf16* __restrict__ dst,
                const float* __restrict__ H, int* __restrict__ col_cnt,
                int* __restrict__ row_cnt, unsigned short* __restrict__ row_idx)
{
    const int t = threadIdx.x;

    if (blockIdx.x >= 256) {
        // ---------------- build_rows (+ col_cnt zero) ----------------
        const int b = blockIdx.x - 256;            // 0..2047
        if (t < 16) col_cnt[b * 16 + t] = 0;       // 2048*16 = E*CSTRIDE

        const int lane = t & 63;
        const int n = b * 4 + (t >> 6);
        const unsigned long long ltm = (1ull << lane) - 1ull;
        int base = 0;

#pragma unroll
        for (int seg = 0; seg < 8; seg++) {
            f32x4 v = *(const f32x4*)(H + (size_t)n * 2048 + seg * 256 + lane * 4);
            unsigned long long bm[4];
#pragma unroll
            for (int j = 0; j < 4; j++) bm[j] = __ballot(v[j] != 0.f);

            int pre = 0;
#pragma unroll
            for (int j = 0; j < 4; j++) {
                if (v[j] != 0.f) {
                    const int slot = base + pre + (int)__popcll(bm[j] & ltm);
                    if (slot < RMAX)
                        row_idx[(size_t)n * RMAX + slot] =
                            (unsigned short)(seg * 256 + lane * 4 + j);
                }
                pre += (int)__popcll(bm[j]);
            }
            base += pre;
        }
        if (lane == 0) row_cnt[n] = (base < RMAX) ? base : RMAX;
        return;
    }

    if (blockIdx.x < 128) {
        // ---------------- combined weights ----------------
        const int combo = blockIdx.x >> 5;         // 4 combos x 32 blocks
        const int i0    = (blockIdx.x & 31) * 8;   // 8 out-rows per block
        const float* __restrict__ Aw = d.aw[combo];
        const float* __restrict__ Bw = d.pw[combo];

        float acc[8];
#pragma unroll
        for (int i = 0; i < 8; i++) acc[i] = 0.f;

#pragma unroll 4
        for (int k = 0; k < 256; k++) {
            const float bv = Bw[k * 256 + t];      // coalesced vector load
#pragma unroll
            for (int i = 0; i < 8; i++)            // wave-uniform scalar loads
                acc[i] += Aw[(i0 + i) * 256 + k] * bv;
        }
        bf16* o = dst + d.cdst[combo];
#pragma unroll
        for (int i = 0; i < 8; i++)
            o[(i0 + i) * 256 + t] = __float2bfloat16(acc[i]);

        // combined bias for these 8 rows: b'[i] = ab[i] + sum_k Aw[i,k]*pb[k]
        {
            const int i  = t >> 5;                 // 8 groups of 32 lanes
            const int kk = (t & 31) * 8;
            float s = 0.f;
#pragma unroll
            for (int u = 0; u < 8; u++)
                s += Aw[(i0 + i) * 256 + kk + u] * d.pb[combo][kk + u];
#pragma unroll
            for (int o2 = 1; o2 < 32; o2 <<= 1) s += __shfl_xor(s, o2);
            if ((t & 31) == 0)
                dst[d.bdst[combo] + i0 + i] =
                    __float2bfloat16(d.ab[combo][i0 + i] + s);
        }
        return;
    }

    // ---------------- straight conversions ----------------
    const int seg = (blockIdx.x - 128) >> 4;       // 8 segs x 16 blocks
    const int blk = (blockIdx.x - 128) & 15;
    const float* __restrict__ s = d.csrc[seg];
    bf16* __restrict__ o = dst + d.coff[seg];
    const int n = d.ccnt[seg];
    for (int i = blk * 256 + t; i < n; i += 16 * 256)
        o[i] = __float2bfloat16(s[i]);
}

// ---------------------------------------------------------------------------
// Mega GEMM: blocks [0,512) compute x0cat = [x0p|k1|v1|q2] (8192x1024) from
// fp32 x_0 via combined weights; blocks [512,576) compute x1cat = [x1p|q1]
// (2048x512) from x_1. Blocks [576,832): column lists derived from the row
// lists (runs alongside / after the GEMM blocks; attn1 is next launch).
// ---------------------------------------------------------------------------
__global__ __launch_bounds__(256, 2)
void gemm_mega(const float* __restrict__ X0, const float* __restrict__ X1,
               const bf16* __restrict__ wc,
               bf16* __restrict__ x0cat, bf16* __restrict__ x1cat,
               const int* __restrict__ row_cnt,
               const unsigned short* __restrict__ row_idx,
               int* __restrict__ col_cnt, unsigned short* __restrict__ col_idx)
{
    __shared__ __align__(16) bf16 As[4 * QSTRIDE];
    __shared__ __align__(16) bf16 Bs[4 * QSTRIDE];

    const int t = threadIdx.x;

    if (blockIdx.x >= 576) {
        // ---------------- build_cols ----------------
        const int g = (blockIdx.x - 576) * 256 + t;   // 65536 = 8192 rows x 8
        const int n = g >> 3;
        const int tt = g & 7;
        const int cnt = row_cnt[n];
        for (int i = tt; i < cnt; i += 8) {
            const int e = row_idx[(size_t)n * RMAX + i];
            const int s = atomicAdd(&col_cnt[e * CSTRIDE], 1);
            if (s < CMAX) col_idx[(size_t)e * CMAX + s] = (unsigned short)n;
        }
        return;
    }

    const int lane = t & 63;
    const int w    = t >> 6;
    const int wm   = (w >> 1) * 64;
    const int wn   = (w & 1) * 64;

    int rt, ct, ostride;
    const float* __restrict__ A;
    const bf16* __restrict__ W;
    const bf16* __restrict__ bias;
    bf16* __restrict__ outp;
    if (blockIdx.x < 512) {
        rt = blockIdx.x >> 3; ct = blockIdx.x & 7;
        A = X0; W = wc + O_MW0; bias = wc + O_MB0; outp = x0cat; ostride = 1024;
    } else {
        const int b = blockIdx.x - 512;
        rt = b >> 2; ct = b & 3;
        A = X1; W = wc + O_MW1; bias = wc + O_MB1; outp = x1cat; ostride = 512;
    }
    const int arow = rt * 128;
    const int tn   = ct * 128;

    f32x4 acc[4][4];
#pragma unroll
    for (int i = 0; i < 4; i++)
#pragma unroll
        for (int j = 0; j < 4; j++)
#pragma unroll
            for (int r = 0; r < 4; r++) acc[i][j][r] = 0.f;

    const int m0 = t >> 2,         q0 = t & 3;
    const int m1 = (t + 256) >> 2, q1 = (t + 256) & 3;
    const int fq = lane >> 4, fr = lane & 15;

    for (int k0 = 0; k0 < 256; k0 += 32) {
        f32x4 a0l = *(const f32x4*)(A + (size_t)(arow + m0) * 256 + k0 + q0 * 8);
        f32x4 a0h = *(const f32x4*)(A + (size_t)(arow + m0) * 256 + k0 + q0 * 8 + 4);
        f32x4 a1l = *(const f32x4*)(A + (size_t)(arow + m1) * 256 + k0 + q1 * 8);
        f32x4 a1h = *(const f32x4*)(A + (size_t)(arow + m1) * 256 + k0 + q1 * 8 + 4);
        union { s16x8 v; bf16 e[8]; } u0, u1;
#pragma unroll
        for (int j = 0; j < 4; j++) {
            u0.e[j] = __float2bfloat16(a0l[j]); u0.e[4 + j] = __float2bfloat16(a0h[j]);
            u1.e[j] = __float2bfloat16(a1l[j]); u1.e[4 + j] = __float2bfloat16(a1h[j]);
        }
        s16x8 sb0 = *(const s16x8*)(W + (size_t)(tn + m0) * 256 + k0 + q0 * 8);
        s16x8 sb1 = *(const s16x8*)(W + (size_t)(tn + m1) * 256 + k0 + q1 * 8);

        __syncthreads();
        *(s16x8*)&As[q0 * QSTRIDE + m0 * 8] = u0.v;
        *(s16x8*)&As[q1 * QSTRIDE + m1 * 8] = u1.v;
        *(s16x8*)&Bs[q0 * QSTRIDE + m0 * 8] = sb0;
        *(s16x8*)&Bs[q1 * QSTRIDE + m1 * 8] = sb1;
        __syncthreads();

        s16x8 af[4], bfv[4];
#pragma unroll
        for (int i = 0; i < 4; i++) {
            af[i]  = *(const s16x8*)&As[fq * QSTRIDE + (wm + i * 16 + fr) * 8];
            bfv[i] = *(const s16x8*)&Bs[fq * QSTRIDE + (wn + i * 16 + fr) * 8];
        }
#pragma unroll
        for (int i = 0; i < 4; i++)
#pragma unroll
            for (int j = 0; j < 4; j++)
                acc[i][j] = __builtin_amdgcn_mfma_f32_16x16x32_bf16(
                    af[i], bfv[j], acc[i][j], 0, 0, 0);
    }

#pragma unroll
    for (int j = 0; j < 4; j++) {
        const int ncol = tn + wn + j * 16 + fr;
        const float bj = __bfloat162float(bias[ncol]);
#pragma unroll
        for (int i = 0; i < 4; i++)
#pragma unroll
            for (int r = 0; r < 4; r++) {
                const int mrow = arow + wm + i * 16 + fq * 4 + r;
                outp[(size_t)mrow * ostride + ncol] = __float2bfloat16(acc[i][j][r] + bj);
            }
    }
}

// ---------------------------------------------------------------------------
// Dual MFMA GEMM (two independent problems, block-range split), bf16 in/out.
// (Used once, for kv2.)
// ---------------------------------------------------------------------------
__global__ __launch_bounds__(256, 2)
void gemm_dual(const bf16* __restrict__ A0, const bf16* __restrict__ W0,
               const bf16* __restrict__ bias0, bf16* __restrict__ out0,
               int N0, int tiles0, int nblk0,
               const bf16* __restrict__ A1, const bf16* __restrict__ W1,
               const bf16* __restrict__ bias1, bf16* __restrict__ out1,
               int N1, int tiles1)
{
    __shared__ __align__(16) bf16 As[4 * QSTRIDE];
    __shared__ __align__(16) bf16 Bs[4 * QSTRIDE];

    const int t    = threadIdx.x;
    const int lane = t & 63;
    const int w    = t >> 6;
    const int wm   = (w >> 1) * 64;
    const int wn   = (w & 1) * 64;

    const bool second = (blockIdx.x >= (unsigned)nblk0);
    const int  bi     = second ? (blockIdx.x - nblk0) : blockIdx.x;
    const bf16* __restrict__ A    = second ? A1 : A0;
    const bf16* __restrict__ W    = second ? W1 : W0;
    const bf16* __restrict__ bias = second ? bias1 : bias0;
    bf16* __restrict__ outB       = second ? out1 : out0;
    const int N      = second ? N1 : N0;
    const int tilesN = second ? tiles1 : tiles0;
    const int tm = (bi / tilesN) * 128;
    const int tn = (bi % tilesN) * 128;

    f32x4 acc[4][4];
#pragma unroll
    for (int i = 0; i < 4; i++)
#pragma unroll
        for (int j = 0; j < 4; j++)
#pragma unroll
            for (int r = 0; r < 4; r++) acc[i][j][r] = 0.f;

    const int m0 = t >> 2,         q0 = t & 3;
    const int m1 = (t + 256) >> 2, q1 = (t + 256) & 3;
    const int fq = lane >> 4, fr = lane & 15;

    for (int k0 = 0; k0 < 256; k0 += 32) {
        s16x8 sa0 = *(const s16x8*)(A + (size_t)(tm + m0) * 256 + k0 + q0 * 8);
        s16x8 sa1 = *(const s16x8*)(A + (size_t)(tm + m1) * 256 + k0 + q1 * 8);
        s16x8 sb0 = *(const s16x8*)(W + (size_t)(tn + m0) * 256 + k0 + q0 * 8);
        s16x8 sb1 = *(const s16x8*)(W + (size_t)(tn + m1) * 256 + k0 + q1 * 8);

        __syncthreads();
        *(s16x8*)&As[q0 * QSTRIDE + m0 * 8] = sa0;
        *(s16x8*)&As[q1 * QSTRIDE + m1 * 8] = sa1;
        *(s16x8*)&Bs[q0 * QSTRIDE + m0 * 8] = sb0;
        *(s16x8*)&Bs[q1 * QSTRIDE + m1 * 8] = sb1;
        __syncthreads();

        s16x8 af[4], bfv[4];
#pragma unroll
        for (int i = 0; i < 4; i++) {
            af[i]  = *(const s16x8*)&As[fq * QSTRIDE + (wm + i * 16 + fr) * 8];
            bfv[i] = *(const s16x8*)&Bs[fq * QSTRIDE + (wn + i * 16 + fr) * 8];
        }
#pragma unroll
        for (int i = 0; i < 4; i++)
#pragma unroll
            for (int j = 0; j < 4; j++)
                acc[i][j] = __builtin_amdgcn_mfma_f32_16x16x32_bf16(
                    af[i], bfv[j], acc[i][j], 0, 0, 0);
    }

#pragma unroll
    for (int j = 0; j < 4; j++) {
        const int ncol = tn + wn + j * 16 + fr;
        const float bj = __bfloat162float(bias[ncol]);
#pragma unroll
        for (int i = 0; i < 4; i++)
#pragma unroll
            for (int r = 0; r < 4; r++) {
                const int mrow = tm + wm + i * 16 + fq * 4 + r;
                outB[(size_t)mrow * N + ncol] = __float2bfloat16(acc[i][j][r] + bj);
            }
    }
}

// ---------------------------------------------------------------------------
// Fused out-proj + residual + LayerNorm. Block = 64 rows x 256 cols.
// y = LN(xp + A@W^T + bias) * g + b -> fp32 d_out (+ optional bf16 copy).
// xp is read with row stride xps (residual lives inside a wider cat buffer).
// ---------------------------------------------------------------------------
__global__ __launch_bounds__(256, 2)
void gemm_ln(const bf16* __restrict__ A, const bf16* __restrict__ W,
             const float* __restrict__ biasF, const bf16* __restrict__ xp, int xps,
             const float* __restrict__ g, const float* __restrict__ b,
             float* __restrict__ outF, bf16* __restrict__ outB)
{
    __shared__ __align__(16) bf16 As[4 * ASTRIDE];
    __shared__ __align__(16) bf16 Bs[4 * BSTRIDE];
    __shared__ float rs1[64], rs2[64];

    const int t    = threadIdx.x;
    const int lane = t & 63;
    const int w    = t >> 6;
    const int fq   = lane >> 4;
    const int fr   = lane & 15;
    const int tm   = blockIdx.x * 64;

    if (t < 64) { rs1[t] = 0.f; rs2[t] = 0.f; }

    f32x4 acc[4][4];
#pragma unroll
    for (int i = 0; i < 4; i++)
#pragma unroll
        for (int j = 0; j < 4; j++)
#pragma unroll
            for (int r = 0; r < 4; r++) acc[i][j][r] = 0.f;

    const int mA = t >> 2, qA = t & 3;

    for (int k0 = 0; k0 < 256; k0 += 32) {
        s16x8 sa = *(const s16x8*)(A + (size_t)(tm + mA) * 256 + k0 + qA * 8);
        s16x8 sb[4];
#pragma unroll
        for (int s = 0; s < 4; s++)
            sb[s] = *(const s16x8*)(W + (size_t)(mA + 64 * s) * 256 + k0 + qA * 8);

        __syncthreads();
        *(s16x8*)&As[qA * ASTRIDE + mA * 8] = sa;
#pragma unroll
        for (int s = 0; s < 4; s++)
            *(s16x8*)&Bs[qA * BSTRIDE + (mA + 64 * s) * 8] = sb[s];
        __syncthreads();

        s16x8 af[4], bfv[4];
#pragma unroll
        for (int i = 0; i < 4; i++) {
            af[i]  = *(const s16x8*)&As[fq * ASTRIDE + (i * 16 + fr) * 8];
            bfv[i] = *(const s16x8*)&Bs[fq * BSTRIDE + (w * 64 + i * 16 + fr) * 8];
        }
#pragma unroll
        for (int i = 0; i < 4; i++)
#pragma unroll
            for (int j = 0; j < 4; j++)
                acc[i][j] = __builtin_amdgcn_mfma_f32_16x16x32_bf16(
                    af[i], bfv[j], acc[i][j], 0, 0, 0);
    }

    float bj[4], gj[4], bbj[4];
    int colv[4];
#pragma unroll
    for (int j = 0; j < 4; j++) {
        colv[j] = w * 64 + j * 16 + fr;
        bj[j]  = biasF[colv[j]];
        gj[j]  = g[colv[j]];
        bbj[j] = b[colv[j]];
    }

#pragma unroll
    for (int i = 0; i < 4; i++) {
#pragma unroll
        for (int r = 0; r < 4; r++) {
            const int row = i * 16 + fq * 4 + r;
            float t1 = 0.f, t2 = 0.f;
#pragma unroll
            for (int j = 0; j < 4; j++) {
                float v = acc[i][j][r] + bj[j]
                        + __bfloat162float(xp[(size_t)(tm + row) * xps + colv[j]]);
                acc[i][j][r] = v;
                t1 += v;
                t2 += v * v;
            }
#pragma unroll
            for (int o = 1; o < 16; o <<= 1) {
                t1 += __shfl_xor(t1, o);
                t2 += __shfl_xor(t2, o);
            }
            if (fr == 0) {
                atomicAdd(&rs1[row], t1);
                atomicAdd(&rs2[row], t2);
            }
        }
    }
    __syncthreads();

#pragma unroll
    for (int i = 0; i < 4; i++) {
#pragma unroll
        for (int r = 0; r < 4; r++) {
            const int row = i * 16 + fq * 4 + r;
            const float mu  = rs1[row] * (1.f / 256.f);
            const float var = rs2[row] * (1.f / 256.f) - mu * mu;
            const float rstd = rsqrtf(var + 1e-5f);
#pragma unroll
            for (int j = 0; j < 4; j++) {
                const float y = (acc[i][j][r] - mu) * rstd * gj[j] + bbj[j];
                outF[(size_t)(tm + row) * 256 + colv[j]] = y;
                if (outB) outB[(size_t)(tm + row) * 256 + colv[j]] = __float2bfloat16(y);
            }
        }
    }
}

// ---------------------------------------------------------------------------
// Sparse masked attention, vectorized gather. Block = query row, wave = head.
// 8 groups x 8 lanes: group = neighbor, lane = 8-dim slice (16 B loads).
// Q/K/V pointers may live inside wider cat buffers (qs/kvs row strides).
// ---------------------------------------------------------------------------
__global__ __launch_bounds__(256)
void sparse_attn(const bf16* __restrict__ Q, int qs,
                 const bf16* __restrict__ Kb, const bf16* __restrict__ Vb, int kvs,
                 const int* __restrict__ cnts, int cstride,
                 const unsigned short* __restrict__ idx,
                 int lmax, int idxmask, bf16* __restrict__ out)
{
    __shared__ float sc[4][CMAX];
    __shared__ unsigned short nls[CMAX];
    const int qi   = blockIdx.x;
    const int h    = threadIdx.x >> 6;
    const int lane = threadIdx.x & 63;
    const int grp  = lane >> 3;
    const int sub  = lane & 7;

    int n = cnts[(size_t)qi * cstride];
    if (n > lmax) n = lmax;

    if (h == 0)
        for (int i = lane; i < n; i += 64)
            nls[i] = (unsigned short)(((int)idx[(size_t)qi * lmax + i]) & idxmask);
    __syncthreads();

    if (n <= 0) {
        out[(size_t)qi * 256 + h * 64 + lane] = __float2bfloat16(0.f);
        return;
    }

    float qv[8];
    {
        union { f32x4 v; unsigned short u[8]; } qu;
        qu.v = *(const f32x4*)(Q + (size_t)qi * qs + h * 64 + sub * 8);
#pragma unroll
        for (int j = 0; j < 8; j++)
            qv[j] = __uint_as_float(((unsigned)qu.u[j]) << 16) * 0.125f;
    }

    float mx = -1e30f;
#pragma unroll 2
    for (int base = 0; base < n; base += 8) {
        const int i = base + grp;
        float s = -1e30f;
        if (i < n) {
            const int nb = nls[i];
            union { f32x4 v; unsigned short u[8]; } ku;
            ku.v = *(const f32x4*)(Kb + (size_t)nb * kvs + h * 64 + sub * 8);
            float a = 0.f;
#pragma unroll
            for (int j = 0; j < 8; j++)
                a += __uint_as_float(((unsigned)ku.u[j]) << 16) * qv[j];
            a += __shfl_xor(a, 1);
            a += __shfl_xor(a, 2);
            a += __shfl_xor(a, 4);
            if (sub == 0) sc[h][i] = a;
            s = a;
        }
        mx = fmaxf(mx, s);
    }
#pragma unroll
    for (int o = 32; o > 0; o >>= 1) mx = fmaxf(mx, __shfl_xor(mx, o));

    float sum = 0.f;
    for (int base = 0; base < n; base += 64) {
        const int i = base + lane;
        if (i < n) {
            const float p = __expf(sc[h][i] - mx);
            sc[h][i] = p;
            sum += p;
        }
    }
#pragma unroll
    for (int o = 32; o > 0; o >>= 1) sum += __shfl_xor(sum, o);
    const float inv = 1.f / sum;

    float oa[8];
#pragma unroll
    for (int j = 0; j < 8; j++) oa[j] = 0.f;
#pragma unroll 2
    for (int base = 0; base < n; base += 8) {
        const int i = base + grp;
        if (i < n) {
            const float p = sc[h][i];
            const int nb = nls[i];
            union { f32x4 v; unsigned short u[8]; } vu;
            vu.v = *(const f32x4*)(Vb + (size_t)nb * kvs + h * 64 + sub * 8);
#pragma unroll
            for (int j = 0; j < 8; j++)
                oa[j] += p * __uint_as_float(((unsigned)vu.u[j]) << 16);
        }
    }
#pragma unroll
    for (int j = 0; j < 8; j++) {
        oa[j] += __shfl_xor(oa[j], 8);
        oa[j] += __shfl_xor(oa[j], 16);
        oa[j] += __shfl_xor(oa[j], 32);
    }
    if (grp == 0) {
        union { s16x8 v; bf16 e[8]; } ou;
#pragma unroll
        for (int j = 0; j < 8; j++) ou.e[j] = __float2bfloat16(oa[j] * inv);
        *(s16x8*)(out + (size_t)qi * 256 + h * 64 + sub * 8) = ou.v;
    }
}

// ---------------------------------------------------------------------------
extern "C" void kernel_launch(void* const* d_in, const int* in_sizes, int n_in,
                              void* d_out, int out_size, void* d_ws, size_t ws_size,
                              hipStream_t stream)
{
    const int N = 8192, E = 2048;

    float* out0 = (float*)d_out;                   // x_0_u [N,256] fp32
    float* out1 = (float*)d_out + (size_t)N * 256; // x_1_u [E,256] fp32

    char* wp = (char*)d_ws;
    auto carve = [&](size_t bytes) { void* p = wp; wp += (bytes + 15) & ~size_t(15); return p; };

    bf16*  wcat    = (bf16*)          carve(657408 * 2);
    int*   col_cnt = (int*)           carve((size_t)E * CSTRIDE * 4);
    int*   row_cnt = (int*)           carve((size_t)N * 4);
    unsigned short* col_idx = (unsigned short*)carve((size_t)E * CMAX * 2);
    unsigned short* row_idx = (unsigned short*)carve((size_t)N * RMAX * 2);
    bf16*  x0cat   = (bf16*) carve((size_t)N * 1024 * 2);  // x0p|k1|v1|q2
    bf16*  x1cat   = (bf16*) carve((size_t)E * 512 * 2);   // x1p|q1
    bf16*  attn1   = (bf16*) carve((size_t)E * 256 * 2);
    bf16*  x1u_b   = (bf16*) carve((size_t)E * 256 * 2);
    bf16*  kv2     = (bf16*) carve((size_t)E * 512 * 2);
    bf16*  attn2   = (bf16*) carve((size_t)N * 256 * 2);

    const float* nw = (const float*)d_in[3];
    const float* nb = (const float*)d_in[4];
    const float* ew = (const float*)d_in[5];
    const float* eb = (const float*)d_in[6];
    const float* w1 = (const float*)d_in[7];   // n2e_in_w [768,256]: Wq1|Wk1|Wv1
    const float* b1 = (const float*)d_in[8];
    const float* w2 = (const float*)d_in[11];  // e2n_in_w [768,256]: Wq2|Wk2|Wv2
    const float* b2 = (const float*)d_in[12];

    PrepDesc pd;
    // combos: C = aw @ pw (out in cdst), b' = ab + aw @ pb (in bdst)
    pd.aw[0] = w1 + 65536;  pd.pw[0] = nw; pd.ab[0] = b1 + 256; pd.pb[0] = nb;
    pd.cdst[0] = O_MW0 + 65536;  pd.bdst[0] = O_MB0 + 256;   // k1
    pd.aw[1] = w1 + 131072; pd.pw[1] = nw; pd.ab[1] = b1 + 512; pd.pb[1] = nb;
    pd.cdst[1] = O_MW0 + 131072; pd.bdst[1] = O_MB0 + 512;   // v1
    pd.aw[2] = w2;          pd.pw[2] = nw; pd.ab[2] = b2;      pd.pb[2] = nb;
    pd.cdst[2] = O_MW0 + 196608; pd.bdst[2] = O_MB0 + 768;   // q2
    pd.aw[3] = w1;          pd.pw[3] = ew; pd.ab[3] = b1;      pd.pb[3] = eb;
    pd.cdst[3] = O_MW1 + 65536;  pd.bdst[3] = O_MB1 + 256;   // q1
    // straight conversions
    const float* csrc[8] = { nw, ew, w2 + 65536, (const float*)d_in[9],
                             (const float*)d_in[13], nb, eb, b2 + 256 };
    const int coff[8] = {O_MW0, O_MW1, O_KV2W, O_O1W, O_O2W, O_MB0, O_MB1, O_KV2B};
    const int ccnt[8] = {65536, 65536, 131072, 65536, 65536, 256, 256, 512};
    for (int i = 0; i < 8; i++) { pd.csrc[i] = csrc[i]; pd.coff[i] = coff[i]; pd.ccnt[i] = ccnt[i]; }

    // 1. fused front: weight prep (256 blocks) + row lists / col_cnt zero (2048)
    prep_front<<<256 + 2048, 256, 0, stream>>>(pd, wcat, (const float*)d_in[2],
                                               col_cnt, row_cnt, row_idx);

    // 2. mega GEMM (x0cat 512 blocks, x1cat 64) + col lists (256)
    gemm_mega<<<576 + 256, 256, 0, stream>>>((const float*)d_in[0],
                                             (const float*)d_in[1], wcat,
                                             x0cat, x1cat,
                                             row_cnt, row_idx, col_cnt, col_idx);

    // ---- stage 1: node -> edge ----
    sparse_attn<<<E, 256, 0, stream>>>(x1cat + 256, 512,
                                       x0cat + 256, x0cat + 512, 1024,
                                       col_cnt, CSTRIDE, col_idx, CMAX, N - 1, attn1);
    gemm_ln<<<E / 64, 256, 0, stream>>>(attn1, wcat + O_O1W, (const float*)d_in[10],
                                        x1cat, 512,
                                        (const float*)d_in[15], (const float*)d_in[16],
                                        out1, x1u_b);

    // ---- stage 2: edge -> node ----
    gemm_dual<<<64, 256, 0, stream>>>(x1u_b, wcat + O_KV2W, wcat + O_KV2B, kv2,
                                      512, 4, 64,
                                      nullptr, nullptr, nullptr, nullptr, 256, 2);
    sparse_attn<<<N, 256, 0, stream>>>(x0cat + 768, 1024, kv2, kv2 + 256, 512,
                                       row_cnt, 1, row_idx, RMAX, E - 1, attn2);
    gemm_ln<<<N / 64, 256, 0, stream>>>(attn2, wcat + O_O2W, (const float*)d_in[14],
                                        x0cat, 1024,
                                        (const float*)d_in[17], (const float*)d_in[18],
                                        out0, nullptr);
}

// Round 4
// 255.799 us; speedup vs baseline: 1.0299x; 1.0299x over previous
//
#include <hip/hip_runtime.h>
#include <hip/hip_bf16.h>

using bf16 = __hip_bfloat16;
typedef __attribute__((ext_vector_type(4))) float  f32x4;
typedef __attribute__((ext_vector_type(8))) short  s16x8;

#define QSTRIDE 1040   // 128*8 + 16 pad (bf16 elems per k-quad block)
#define ASTRIDE 520    // 64*8 + 8 pad   (gemm_ln A tile)
#define BSTRIDE 2064   // 256*8 + 16 pad (gemm_ln B tile)
#define YSTRIDE 520    // y-tile kq stride (64*8 + 8 pad -> 1040B, breaks bank alias)
#define CMAX 256
#define RMAX 128
#define CSTRIDE 16     // col_cnt padding: one counter per 64B cache line

// wcat element offsets (all 8-elem aligned)
#define O_MW0  0        // mega W0 [1024,256]: node_w | Wk1@nw | Wv1@nw | Wq2@nw
#define O_MB0  262144   // mega b0 [1024]
#define O_MW1  263168   // mega W1 [512,256]: edge_w | Wq1@ew
#define O_MB1  394240   // mega b1 [512]
#define O_KV2W 394752   // e2n Wk,Wv [512,256]
#define O_KV2B 525824   // e2n bk,bv [512]
#define O_O1W  526336   // n2e_out_w [256,256]
#define O_O2W  591872   // e2n_out_w [256,256]
// total 657408 elems

// ---------------------------------------------------------------------------
// Fused front kernel. Blocks [0,128): combined-weight products
// C = attnW @ projW (bf16 out) + combined bias b' = ab + attnW@pb.
// Aw rows are staged in LDS (coalesced, once) so the k-loop is pure
// Bw-streaming with 16-deep MLP (was: 4-deep + wave-uniform scalar loads,
// the measured 43us latency tail).
// Blocks [128,256): straight fp32->bf16 weight conversion segments.
// Blocks [256,2304): row lists via wave-per-row ballot compaction
// (no atomics/barriers/LDS) + col_cnt zero-fill.
// ---------------------------------------------------------------------------
struct PrepDesc {
    const float* aw[4]; const float* pw[4];
    const float* ab[4]; const float* pb[4];
    int cdst[4]; int bdst[4];
    const float* csrc[8]; int coff[8]; int ccnt[8];
};

__global__ __launch_bounds__(256)
void prep_front(PrepDesc d, bf16* __restrict__ dst,
                const float* __restrict__ H, int* __restrict__ col_cnt,
                int* __restrict__ row_cnt, unsigned short* __restrict__ row_idx)
{
    __shared__ float aws[2048];                    // 8 Aw rows (8 KB)
    const int t = threadIdx.x;

    if (blockIdx.x >= 256) {
        // ---------------- build_rows (+ col_cnt zero) ----------------
        const int b = blockIdx.x - 256;            // 0..2047
        if (t < 16) col_cnt[b * 16 + t] = 0;       // 2048*16 = E*CSTRIDE

        const int lane = t & 63;
        const int n = b * 4 + (t >> 6);
        const unsigned long long ltm = (1ull << lane) - 1ull;
        int base = 0;

#pragma unroll
        for (int seg = 0; seg < 8; seg++) {
            f32x4 v = *(const f32x4*)(H + (size_t)n * 2048 + seg * 256 + lane * 4);
            unsigned long long bm[4];
#pragma unroll
            for (int j = 0; j < 4; j++) bm[j] = __ballot(v[j] != 0.f);

            int pre = 0;
#pragma unroll
            for (int j = 0; j < 4; j++) {
                if (v[j] != 0.f) {
                    const int slot = base + pre + (int)__popcll(bm[j] & ltm);
                    if (slot < RMAX)
                        row_idx[(size_t)n * RMAX + slot] =
                            (unsigned short)(seg * 256 + lane * 4 + j);
                }
                pre += (int)__popcll(bm[j]);
            }
            base += pre;
        }
        if (lane == 0) row_cnt[n] = (base < RMAX) ? base : RMAX;
        return;
    }

    if (blockIdx.x < 128) {
        // ---------------- combined weights ----------------
        const int combo = blockIdx.x >> 5;         // 4 combos x 32 blocks
        const int i0    = (blockIdx.x & 31) * 8;   // 8 out-rows per block
        const float* __restrict__ Aw = d.aw[combo];
        const float* __restrict__ Bw = d.pw[combo];

#pragma unroll
        for (int i = 0; i < 8; i++)                // stage Aw rows, coalesced
            aws[i * 256 + t] = Aw[(size_t)(i0 + i) * 256 + t];
        __syncthreads();

        float acc[8];
#pragma unroll
        for (int i = 0; i < 8; i++) acc[i] = 0.f;

#pragma unroll 16
        for (int k = 0; k < 256; k++) {
            const float bv = Bw[k * 256 + t];      // coalesced, 16-deep MLP
#pragma unroll
            for (int i = 0; i < 8; i++)            // LDS broadcast (free)
                acc[i] += aws[i * 256 + k] * bv;
        }
        bf16* o = dst + d.cdst[combo];
#pragma unroll
        for (int i = 0; i < 8; i++)
            o[(i0 + i) * 256 + t] = __float2bfloat16(acc[i]);

        // combined bias for these 8 rows: b'[i] = ab[i] + sum_k Aw[i,k]*pb[k]
        {
            const int i  = t >> 5;                 // 8 groups of 32 lanes
            const int kk = (t & 31) * 8;
            float s = 0.f;
#pragma unroll
            for (int u = 0; u < 8; u++)
                s += aws[i * 256 + kk + u] * d.pb[combo][kk + u];
#pragma unroll
            for (int o2 = 1; o2 < 32; o2 <<= 1) s += __shfl_xor(s, o2);
            if ((t & 31) == 0)
                dst[d.bdst[combo] + i0 + i] =
                    __float2bfloat16(d.ab[combo][i0 + i] + s);
        }
        return;
    }

    // ---------------- straight conversions ----------------
    const int seg = (blockIdx.x - 128) >> 4;       // 8 segs x 16 blocks
    const int blk = (blockIdx.x - 128) & 15;
    const float* __restrict__ s = d.csrc[seg];
    bf16* __restrict__ o = dst + d.coff[seg];
    const int n = d.ccnt[seg];
    for (int i = blk * 256 + t; i < n; i += 16 * 256)
        o[i] = __float2bfloat16(s[i]);
}

// ---------------------------------------------------------------------------
// Mega GEMM: blocks [0,512) compute x0cat = [x0p|k1|v1|q2] (8192x1024) from
// fp32 x_0 via combined weights; blocks [512,576) compute x1cat = [x1p|q1]
// (2048x512) from x_1. Blocks [576,832): column lists derived from the row
// lists (runs alongside / after the GEMM blocks; attn1 is next launch).
// ---------------------------------------------------------------------------
__global__ __launch_bounds__(256, 2)
void gemm_mega(const float* __restrict__ X0, const float* __restrict__ X1,
               const bf16* __restrict__ wc,
               bf16* __restrict__ x0cat, bf16* __restrict__ x1cat,
               const int* __restrict__ row_cnt,
               const unsigned short* __restrict__ row_idx,
               int* __restrict__ col_cnt, unsigned short* __restrict__ col_idx)
{
    __shared__ __align__(16) bf16 As[4 * QSTRIDE];
    __shared__ __align__(16) bf16 Bs[4 * QSTRIDE];

    const int t = threadIdx.x;

    if (blockIdx.x >= 576) {
        // ---------------- build_cols ----------------
        const int g = (blockIdx.x - 576) * 256 + t;   // 65536 = 8192 rows x 8
        const int n = g >> 3;
        const int tt = g & 7;
        const int cnt = row_cnt[n];
        for (int i = tt; i < cnt; i += 8) {
            const int e = row_idx[(size_t)n * RMAX + i];
            const int s = atomicAdd(&col_cnt[e * CSTRIDE], 1);
            if (s < CMAX) col_idx[(size_t)e * CMAX + s] = (unsigned short)n;
        }
        return;
    }

    const int lane = t & 63;
    const int w    = t >> 6;
    const int wm   = (w >> 1) * 64;
    const int wn   = (w & 1) * 64;

    int rt, ct, ostride;
    const float* __restrict__ A;
    const bf16* __restrict__ W;
    const bf16* __restrict__ bias;
    bf16* __restrict__ outp;
    if (blockIdx.x < 512) {
        rt = blockIdx.x >> 3; ct = blockIdx.x & 7;
        A = X0; W = wc + O_MW0; bias = wc + O_MB0; outp = x0cat; ostride = 1024;
    } else {
        const int b = blockIdx.x - 512;
        rt = b >> 2; ct = b & 3;
        A = X1; W = wc + O_MW1; bias = wc + O_MB1; outp = x1cat; ostride = 512;
    }
    const int arow = rt * 128;
    const int tn   = ct * 128;

    f32x4 acc[4][4];
#pragma unroll
    for (int i = 0; i < 4; i++)
#pragma unroll
        for (int j = 0; j < 4; j++)
#pragma unroll
            for (int r = 0; r < 4; r++) acc[i][j][r] = 0.f;

    const int m0 = t >> 2,         q0 = t & 3;
    const int m1 = (t + 256) >> 2, q1 = (t + 256) & 3;
    const int fq = lane >> 4, fr = lane & 15;

    for (int k0 = 0; k0 < 256; k0 += 32) {
        f32x4 a0l = *(const f32x4*)(A + (size_t)(arow + m0) * 256 + k0 + q0 * 8);
        f32x4 a0h = *(const f32x4*)(A + (size_t)(arow + m0) * 256 + k0 + q0 * 8 + 4);
        f32x4 a1l = *(const f32x4*)(A + (size_t)(arow + m1) * 256 + k0 + q1 * 8);
        f32x4 a1h = *(const f32x4*)(A + (size_t)(arow + m1) * 256 + k0 + q1 * 8 + 4);
        union { s16x8 v; bf16 e[8]; } u0, u1;
#pragma unroll
        for (int j = 0; j < 4; j++) {
            u0.e[j] = __float2bfloat16(a0l[j]); u0.e[4 + j] = __float2bfloat16(a0h[j]);
            u1.e[j] = __float2bfloat16(a1l[j]); u1.e[4 + j] = __float2bfloat16(a1h[j]);
        }
        s16x8 sb0 = *(const s16x8*)(W + (size_t)(tn + m0) * 256 + k0 + q0 * 8);
        s16x8 sb1 = *(const s16x8*)(W + (size_t)(tn + m1) * 256 + k0 + q1 * 8);

        __syncthreads();
        *(s16x8*)&As[q0 * QSTRIDE + m0 * 8] = u0.v;
        *(s16x8*)&As[q1 * QSTRIDE + m1 * 8] = u1.v;
        *(s16x8*)&Bs[q0 * QSTRIDE + m0 * 8] = sb0;
        *(s16x8*)&Bs[q1 * QSTRIDE + m1 * 8] = sb1;
        __syncthreads();

        s16x8 af[4], bfv[4];
#pragma unroll
        for (int i = 0; i < 4; i++) {
            af[i]  = *(const s16x8*)&As[fq * QSTRIDE + (wm + i * 16 + fr) * 8];
            bfv[i] = *(const s16x8*)&Bs[fq * QSTRIDE + (wn + i * 16 + fr) * 8];
        }
#pragma unroll
        for (int i = 0; i < 4; i++)
#pragma unroll
            for (int j = 0; j < 4; j++)
                acc[i][j] = __builtin_amdgcn_mfma_f32_16x16x32_bf16(
                    af[i], bfv[j], acc[i][j], 0, 0, 0);
    }

#pragma unroll
    for (int j = 0; j < 4; j++) {
        const int ncol = tn + wn + j * 16 + fr;
        const float bj = __bfloat162float(bias[ncol]);
#pragma unroll
        for (int i = 0; i < 4; i++)
#pragma unroll
            for (int r = 0; r < 4; r++) {
                const int mrow = arow + wm + i * 16 + fq * 4 + r;
                outp[(size_t)mrow * ostride + ncol] = __float2bfloat16(acc[i][j][r] + bj);
            }
    }
}

// ---------------------------------------------------------------------------
// Fused out-proj + residual + LayerNorm (+ optional second GEMM: kv = y@W2^T).
// Block = 64 rows x 256 cols. y = LN(xp + A@W^T + bias)*g + b -> fp32 outF.
// If W2 != null: y (bf16) is kept in an LDS A-operand tile and the block
// additionally computes kvout[64 x 512] = y @ W2^T + bias2 via MFMA with W2
// fragments read directly from global (L2-resident). This removes the
// separate kv2 GEMM launch and the x1u round-trip through HBM.
// ---------------------------------------------------------------------------
__global__ __launch_bounds__(256)
void gemm_ln(const bf16* __restrict__ A, const bf16* __restrict__ W,
             const float* __restrict__ biasF, const bf16* __restrict__ xp, int xps,
             const float* __restrict__ g, const float* __restrict__ b,
             float* __restrict__ outF,
             const bf16* __restrict__ W2, const bf16* __restrict__ bias2,
             bf16* __restrict__ kvout)
{
    __shared__ __align__(16) bf16 As[4 * ASTRIDE];
    __shared__ __align__(16) bf16 Bs[4 * BSTRIDE];
    __shared__ __align__(16) bf16 Ys[32 * YSTRIDE];   // y as [kq][row][8]
    __shared__ float rs1[64], rs2[64];

    const int t    = threadIdx.x;
    const int lane = t & 63;
    const int w    = t >> 6;
    const int fq   = lane >> 4;
    const int fr   = lane & 15;
    const int tm   = blockIdx.x * 64;

    if (t < 64) { rs1[t] = 0.f; rs2[t] = 0.f; }

    f32x4 acc[4][4];
#pragma unroll
    for (int i = 0; i < 4; i++)
#pragma unroll
        for (int j = 0; j < 4; j++)
#pragma unroll
            for (int r = 0; r < 4; r++) acc[i][j][r] = 0.f;

    const int mA = t >> 2, qA = t & 3;

    for (int k0 = 0; k0 < 256; k0 += 32) {
        s16x8 sa = *(const s16x8*)(A + (size_t)(tm + mA) * 256 + k0 + qA * 8);
        s16x8 sb[4];
#pragma unroll
        for (int s = 0; s < 4; s++)
            sb[s] = *(const s16x8*)(W + (size_t)(mA + 64 * s) * 256 + k0 + qA * 8);

        __syncthreads();
        *(s16x8*)&As[qA * ASTRIDE + mA * 8] = sa;
#pragma unroll
        for (int s = 0; s < 4; s++)
            *(s16x8*)&Bs[qA * BSTRIDE + (mA + 64 * s) * 8] = sb[s];
        __syncthreads();

        s16x8 af[4], bfv[4];
#pragma unroll
        for (int i = 0; i < 4; i++) {
            af[i]  = *(const s16x8*)&As[fq * ASTRIDE + (i * 16 + fr) * 8];
            bfv[i] = *(const s16x8*)&Bs[fq * BSTRIDE + (w * 64 + i * 16 + fr) * 8];
        }
#pragma unroll
        for (int i = 0; i < 4; i++)
#pragma unroll
            for (int j = 0; j < 4; j++)
                acc[i][j] = __builtin_amdgcn_mfma_f32_16x16x32_bf16(
                    af[i], bfv[j], acc[i][j], 0, 0, 0);
    }

    float bj[4], gj[4], bbj[4];
    int colv[4];
#pragma unroll
    for (int j = 0; j < 4; j++) {
        colv[j] = w * 64 + j * 16 + fr;
        bj[j]  = biasF[colv[j]];
        gj[j]  = g[colv[j]];
        bbj[j] = b[colv[j]];
    }

#pragma unroll
    for (int i = 0; i < 4; i++) {
#pragma unroll
        for (int r = 0; r < 4; r++) {
            const int row = i * 16 + fq * 4 + r;
            float t1 = 0.f, t2 = 0.f;
#pragma unroll
            for (int j = 0; j < 4; j++) {
                float v = acc[i][j][r] + bj[j]
                        + __bfloat162float(xp[(size_t)(tm + row) * xps + colv[j]]);
                acc[i][j][r] = v;
                t1 += v;
                t2 += v * v;
            }
#pragma unroll
            for (int o = 1; o < 16; o <<= 1) {
                t1 += __shfl_xor(t1, o);
                t2 += __shfl_xor(t2, o);
            }
            if (fr == 0) {
                atomicAdd(&rs1[row], t1);
                atomicAdd(&rs2[row], t2);
            }
        }
    }
    __syncthreads();

#pragma unroll
    for (int i = 0; i < 4; i++) {
#pragma unroll
        for (int r = 0; r < 4; r++) {
            const int row = i * 16 + fq * 4 + r;
            const float mu  = rs1[row] * (1.f / 256.f);
            const float var = rs2[row] * (1.f / 256.f) - mu * mu;
            const float rstd = rsqrtf(var + 1e-5f);
#pragma unroll
            for (int j = 0; j < 4; j++) {
                const float y = (acc[i][j][r] - mu) * rstd * gj[j] + bbj[j];
                outF[(size_t)(tm + row) * 256 + colv[j]] = y;
                if (kvout) {
                    const int c = colv[j];
                    Ys[(c >> 3) * YSTRIDE + row * 8 + (c & 7)] = __float2bfloat16(y);
                }
            }
        }
    }

    if (!kvout) return;

    // ---------------- phase 2: kv = y @ W2^T + bias2 ----------------
    __syncthreads();
    const int wc0 = w * 128;
#pragma unroll
    for (int chunk = 0; chunk < 2; chunk++) {
        const int cbase = wc0 + chunk * 64;
        f32x4 a2[4][4];
#pragma unroll
        for (int i = 0; i < 4; i++)
#pragma unroll
            for (int j = 0; j < 4; j++)
#pragma unroll
                for (int r = 0; r < 4; r++) a2[i][j][r] = 0.f;

        for (int k0 = 0; k0 < 256; k0 += 32) {
            s16x8 af[4], bv[4];
#pragma unroll
            for (int i = 0; i < 4; i++)
                af[i] = *(const s16x8*)&Ys[(k0 / 8 + fq) * YSTRIDE + (i * 16 + fr) * 8];
#pragma unroll
            for (int j = 0; j < 4; j++)
                bv[j] = *(const s16x8*)(W2 + (size_t)(cbase + j * 16 + fr) * 256 + k0 + fq * 8);
#pragma unroll
            for (int i = 0; i < 4; i++)
#pragma unroll
                for (int j = 0; j < 4; j++)
                    a2[i][j] = __builtin_amdgcn_mfma_f32_16x16x32_bf16(
                        af[i], bv[j], a2[i][j], 0, 0, 0);
        }

#pragma unroll
        for (int j = 0; j < 4; j++) {
            const int col = cbase + j * 16 + fr;
            const float bb = __bfloat162float(bias2[col]);
#pragma unroll
            for (int i = 0; i < 4; i++)
#pragma unroll
                for (int r = 0; r < 4; r++) {
                    const int row = i * 16 + fq * 4 + r;
                    kvout[(size_t)(tm + row) * 512 + col] = __float2bfloat16(a2[i][j][r] + bb);
                }
        }
    }
}

// ---------------------------------------------------------------------------
// Sparse masked attention, vectorized gather. Block = query row, wave = head.
// 8 groups x 8 lanes: group = neighbor, lane = 8-dim slice (16 B loads).
// Q/K/V pointers may live inside wider cat buffers (qs/kvs row strides).
// ---------------------------------------------------------------------------
__global__ __launch_bounds__(256)
void sparse_attn(const bf16* __restrict__ Q, int qs,
                 const bf16* __restrict__ Kb, const bf16* __restrict__ Vb, int kvs,
                 const int* __restrict__ cnts, int cstride,
                 const unsigned short* __restrict__ idx,
                 int lmax, int idxmask, bf16* __restrict__ out)
{
    __shared__ float sc[4][CMAX];
    __shared__ unsigned short nls[CMAX];
    const int qi   = blockIdx.x;
    const int h    = threadIdx.x >> 6;
    const int lane = threadIdx.x & 63;
    const int grp  = lane >> 3;
    const int sub  = lane & 7;

    int n = cnts[(size_t)qi * cstride];
    if (n > lmax) n = lmax;

    if (h == 0)
        for (int i = lane; i < n; i += 64)
            nls[i] = (unsigned short)(((int)idx[(size_t)qi * lmax + i]) & idxmask);
    __syncthreads();

    if (n <= 0) {
        out[(size_t)qi * 256 + h * 64 + lane] = __float2bfloat16(0.f);
        return;
    }

    float qv[8];
    {
        union { f32x4 v; unsigned short u[8]; } qu;
        qu.v = *(const f32x4*)(Q + (size_t)qi * qs + h * 64 + sub * 8);
#pragma unroll
        for (int j = 0; j < 8; j++)
            qv[j] = __uint_as_float(((unsigned)qu.u[j]) << 16) * 0.125f;
    }

    float mx = -1e30f;
#pragma unroll 2
    for (int base = 0; base < n; base += 8) {
        const int i = base + grp;
        float s = -1e30f;
        if (i < n) {
            const int nb = nls[i];
            union { f32x4 v; unsigned short u[8]; } ku;
            ku.v = *(const f32x4*)(Kb + (size_t)nb * kvs + h * 64 + sub * 8);
            float a = 0.f;
#pragma unroll
            for (int j = 0; j < 8; j++)
                a += __uint_as_float(((unsigned)ku.u[j]) << 16) * qv[j];
            a += __shfl_xor(a, 1);
            a += __shfl_xor(a, 2);
            a += __shfl_xor(a, 4);
            if (sub == 0) sc[h][i] = a;
            s = a;
        }
        mx = fmaxf(mx, s);
    }
#pragma unroll
    for (int o = 32; o > 0; o >>= 1) mx = fmaxf(mx, __shfl_xor(mx, o));

    float sum = 0.f;
    for (int base = 0; base < n; base += 64) {
        const int i = base + lane;
        if (i < n) {
            const float p = __expf(sc[h][i] - mx);
            sc[h][i] = p;
            sum += p;
        }
    }
#pragma unroll
    for (int o = 32; o > 0; o >>= 1) sum += __shfl_xor(sum, o);
    const float inv = 1.f / sum;

    float oa[8];
#pragma unroll
    for (int j = 0; j < 8; j++) oa[j] = 0.f;
#pragma unroll 2
    for (int base = 0; base < n; base += 8) {
        const int i = base + grp;
        if (i < n) {
            const float p = sc[h][i];
            const int nb = nls[i];
            union { f32x4 v; unsigned short u[8]; } vu;
            vu.v = *(const f32x4*)(Vb + (size_t)nb * kvs + h * 64 + sub * 8);
#pragma unroll
            for (int j = 0; j < 8; j++)
                oa[j] += p * __uint_as_float(((unsigned)vu.u[j]) << 16);
        }
    }
#pragma unroll
    for (int j = 0; j < 8; j++) {
        oa[j] += __shfl_xor(oa[j], 8);
        oa[j] += __shfl_xor(oa[j], 16);
        oa[j] += __shfl_xor(oa[j], 32);
    }
    if (grp == 0) {
        union { s16x8 v; bf16 e[8]; } ou;
#pragma unroll
        for (int j = 0; j < 8; j++) ou.e[j] = __float2bfloat16(oa[j] * inv);
        *(s16x8*)(out + (size_t)qi * 256 + h * 64 + sub * 8) = ou.v;
    }
}

// ---------------------------------------------------------------------------
extern "C" void kernel_launch(void* const* d_in, const int* in_sizes, int n_in,
                              void* d_out, int out_size, void* d_ws, size_t ws_size,
                              hipStream_t stream)
{
    const int N = 8192, E = 2048;

    float* out0 = (float*)d_out;                   // x_0_u [N,256] fp32
    float* out1 = (float*)d_out + (size_t)N * 256; // x_1_u [E,256] fp32

    char* wp = (char*)d_ws;
    auto carve = [&](size_t bytes) { void* p = wp; wp += (bytes + 15) & ~size_t(15); return p; };

    bf16*  wcat    = (bf16*)          carve(657408 * 2);
    int*   col_cnt = (int*)           carve((size_t)E * CSTRIDE * 4);
    int*   row_cnt = (int*)           carve((size_t)N * 4);
    unsigned short* col_idx = (unsigned short*)carve((size_t)E * CMAX * 2);
    unsigned short* row_idx = (unsigned short*)carve((size_t)N * RMAX * 2);
    bf16*  x0cat   = (bf16*) carve((size_t)N * 1024 * 2);  // x0p|k1|v1|q2
    bf16*  x1cat   = (bf16*) carve((size_t)E * 512 * 2);   // x1p|q1
    bf16*  attn1   = (bf16*) carve((size_t)E * 256 * 2);
    bf16*  kv2     = (bf16*) carve((size_t)E * 512 * 2);
    bf16*  attn2   = (bf16*) carve((size_t)N * 256 * 2);

    const float* nw = (const float*)d_in[3];
    const float* nb = (const float*)d_in[4];
    const float* ew = (const float*)d_in[5];
    const float* eb = (const float*)d_in[6];
    const float* w1 = (const float*)d_in[7];   // n2e_in_w [768,256]: Wq1|Wk1|Wv1
    const float* b1 = (const float*)d_in[8];
    const float* w2 = (const float*)d_in[11];  // e2n_in_w [768,256]: Wq2|Wk2|Wv2
    const float* b2 = (const float*)d_in[12];

    PrepDesc pd;
    // combos: C = aw @ pw (out in cdst), b' = ab + aw @ pb (in bdst)
    pd.aw[0] = w1 + 65536;  pd.pw[0] = nw; pd.ab[0] = b1 + 256; pd.pb[0] = nb;
    pd.cdst[0] = O_MW0 + 65536;  pd.bdst[0] = O_MB0 + 256;   // k1
    pd.aw[1] = w1 + 131072; pd.pw[1] = nw; pd.ab[1] = b1 + 512; pd.pb[1] = nb;
    pd.cdst[1] = O_MW0 + 131072; pd.bdst[1] = O_MB0 + 512;   // v1
    pd.aw[2] = w2;          pd.pw[2] = nw; pd.ab[2] = b2;      pd.pb[2] = nb;
    pd.cdst[2] = O_MW0 + 196608; pd.bdst[2] = O_MB0 + 768;   // q2
    pd.aw[3] = w1;          pd.pw[3] = ew; pd.ab[3] = b1;      pd.pb[3] = eb;
    pd.cdst[3] = O_MW1 + 65536;  pd.bdst[3] = O_MB1 + 256;   // q1
    // straight conversions
    const float* csrc[8] = { nw, ew, w2 + 65536, (const float*)d_in[9],
                             (const float*)d_in[13], nb, eb, b2 + 256 };
    const int coff[8] = {O_MW0, O_MW1, O_KV2W, O_O1W, O_O2W, O_MB0, O_MB1, O_KV2B};
    const int ccnt[8] = {65536, 65536, 131072, 65536, 65536, 256, 256, 512};
    for (int i = 0; i < 8; i++) { pd.csrc[i] = csrc[i]; pd.coff[i] = coff[i]; pd.ccnt[i] = ccnt[i]; }

    // 1. fused front: weight prep (256 blocks) + row lists / col_cnt zero (2048)
    prep_front<<<256 + 2048, 256, 0, stream>>>(pd, wcat, (const float*)d_in[2],
                                               col_cnt, row_cnt, row_idx);

    // 2. mega GEMM (x0cat 512 blocks, x1cat 64) + col lists (256)
    gemm_mega<<<576 + 256, 256, 0, stream>>>((const float*)d_in[0],
                                             (const float*)d_in[1], wcat,
                                             x0cat, x1cat,
                                             row_cnt, row_idx, col_cnt, col_idx);

    // ---- stage 1: node -> edge ----
    sparse_attn<<<E, 256, 0, stream>>>(x1cat + 256, 512,
                                       x0cat + 256, x0cat + 512, 1024,
                                       col_cnt, CSTRIDE, col_idx, CMAX, N - 1, attn1);
    // ln1 + fused kv2 = x1u @ Wkv2^T (removes the gemm_dual launch)
    gemm_ln<<<E / 64, 256, 0, stream>>>(attn1, wcat + O_O1W, (const float*)d_in[10],
                                        x1cat, 512,
                                        (const float*)d_in[15], (const float*)d_in[16],
                                        out1,
                                        wcat + O_KV2W, wcat + O_KV2B, kv2);

    // ---- stage 2: edge -> node ----
    sparse_attn<<<N, 256, 0, stream>>>(x0cat + 768, 1024, kv2, kv2 + 256, 512,
                                       row_cnt, 1, row_idx, RMAX, E - 1, attn2);
    gemm_ln<<<N / 64, 256, 0, stream>>>(attn2, wcat + O_O2W, (const float*)d_in[14],
                                        x0cat, 1024,
                                        (const float*)d_in[17], (const float*)d_in[18],
                                        out0,
                                        nullptr, nullptr, nullptr);
}

// Round 6
// 254.338 us; speedup vs baseline: 1.0358x; 1.0057x over previous
//
#include <hip/hip_runtime.h>
#include <hip/hip_bf16.h>

using bf16 = __hip_bfloat16;
typedef __attribute__((ext_vector_type(4))) float  f32x4;
typedef __attribute__((ext_vector_type(8))) short  s16x8;

#define QSTRIDE 1040   // 128*8 + 16 pad (bf16 elems per k-quad block)
#define ASTRIDE 520    // 64*8 + 8 pad   (gemm_ln A tile)
#define BSTRIDE 2064   // 256*8 + 16 pad (gemm_ln B tile)
#define YSTRIDE 520    // y-tile kq stride
#define CMAX 256
#define RMAX 128
#define CSTRIDE 16     // col_cnt padding: one counter per 64B cache line

// wcat element offsets (all 8-elem aligned)
#define O_MW0  0        // mega W0 [1024,256]: node_w | Wk1@nw | Wv1@nw | Wq2@nw
#define O_MB0  262144   // mega b0 [1024]
#define O_MW1  263168   // mega W1 [512,256]: edge_w | Wq1@ew
#define O_MB1  394240   // mega b1 [512]
#define O_KV2W 394752   // e2n Wk,Wv [512,256]
#define O_KV2B 525824   // e2n bk,bv [512]
#define O_O1W  526336   // n2e_out_w [256,256]
#define O_O2W  591872   // e2n_out_w [256,256]

// ---------------------------------------------------------------------------
// Fused front kernel (identical to round-4 known-good).
// ---------------------------------------------------------------------------
struct PrepDesc {
    const float* aw[4]; const float* pw[4];
    const float* ab[4]; const float* pb[4];
    int cdst[4]; int bdst[4];
    const float* csrc[8]; int coff[8]; int ccnt[8];
};

__global__ __launch_bounds__(256)
void prep_front(PrepDesc d, bf16* __restrict__ dst,
                const float* __restrict__ H, int* __restrict__ col_cnt,
                int* __restrict__ row_cnt, unsigned short* __restrict__ row_idx)
{
    __shared__ float aws[2048];
    const int t = threadIdx.x;

    if (blockIdx.x >= 256) {
        // ---------------- build_rows (+ col_cnt zero) ----------------
        const int b = blockIdx.x - 256;            // 0..2047
        if (t < 16) col_cnt[b * 16 + t] = 0;

        const int lane = t & 63;
        const int n = b * 4 + (t >> 6);
        const unsigned long long ltm = (1ull << lane) - 1ull;
        int base = 0;

#pragma unroll
        for (int seg = 0; seg < 8; seg++) {
            f32x4 v = *(const f32x4*)(H + (size_t)n * 2048 + seg * 256 + lane * 4);
            unsigned long long bm[4];
#pragma unroll
            for (int j = 0; j < 4; j++) bm[j] = __ballot(v[j] != 0.f);

            int pre = 0;
#pragma unroll
            for (int j = 0; j < 4; j++) {
                if (v[j] != 0.f) {
                    const int slot = base + pre + (int)__popcll(bm[j] & ltm);
                    if (slot < RMAX)
                        row_idx[(size_t)n * RMAX + slot] =
                            (unsigned short)(seg * 256 + lane * 4 + j);
                }
                pre += (int)__popcll(bm[j]);
            }
            base += pre;
        }
        if (lane == 0) row_cnt[n] = (base < RMAX) ? base : RMAX;
        return;
    }

    if (blockIdx.x < 128) {
        // ---------------- combined weights (LDS-staged Aw) ----------------
        const int combo = blockIdx.x >> 5;
        const int i0    = (blockIdx.x & 31) * 8;
        const float* __restrict__ Aw = d.aw[combo];
        const float* __restrict__ Bw = d.pw[combo];

#pragma unroll
        for (int i = 0; i < 8; i++)
            aws[i * 256 + t] = Aw[(size_t)(i0 + i) * 256 + t];
        __syncthreads();

        float acc[8];
#pragma unroll
        for (int i = 0; i < 8; i++) acc[i] = 0.f;

#pragma unroll 16
        for (int k = 0; k < 256; k++) {
            const float bv = Bw[k * 256 + t];
#pragma unroll
            for (int i = 0; i < 8; i++)
                acc[i] += aws[i * 256 + k] * bv;
        }
        bf16* o = dst + d.cdst[combo];
#pragma unroll
        for (int i = 0; i < 8; i++)
            o[(i0 + i) * 256 + t] = __float2bfloat16(acc[i]);

        {
            const int i  = t >> 5;
            const int kk = (t & 31) * 8;
            float s = 0.f;
#pragma unroll
            for (int u = 0; u < 8; u++)
                s += aws[i * 256 + kk + u] * d.pb[combo][kk + u];
#pragma unroll
            for (int o2 = 1; o2 < 32; o2 <<= 1) s += __shfl_xor(s, o2);
            if ((t & 31) == 0)
                dst[d.bdst[combo] + i0 + i] =
                    __float2bfloat16(d.ab[combo][i0 + i] + s);
        }
        return;
    }

    // ---------------- straight conversions ----------------
    const int seg = (blockIdx.x - 128) >> 4;
    const int blk = (blockIdx.x - 128) & 15;
    const float* __restrict__ s = d.csrc[seg];
    bf16* __restrict__ o = dst + d.coff[seg];
    const int n = d.ccnt[seg];
    for (int i = blk * 256 + t; i < n; i += 16 * 256)
        o[i] = __float2bfloat16(s[i]);
}

// ---------------------------------------------------------------------------
// Mega GEMM + build_cols (identical to round-4 known-good).
// ---------------------------------------------------------------------------
__global__ __launch_bounds__(256, 2)
void gemm_mega(const float* __restrict__ X0, const float* __restrict__ X1,
               const bf16* __restrict__ wc,
               bf16* __restrict__ x0cat, bf16* __restrict__ x1cat,
               const int* __restrict__ row_cnt,
               const unsigned short* __restrict__ row_idx,
               int* __restrict__ col_cnt, unsigned short* __restrict__ col_idx)
{
    __shared__ __align__(16) bf16 As[4 * QSTRIDE];
    __shared__ __align__(16) bf16 Bs[4 * QSTRIDE];

    const int t = threadIdx.x;

    if (blockIdx.x >= 576) {
        const int g = (blockIdx.x - 576) * 256 + t;
        const int n = g >> 3;
        const int tt = g & 7;
        const int cnt = row_cnt[n];
        for (int i = tt; i < cnt; i += 8) {
            const int e = row_idx[(size_t)n * RMAX + i];
            const int s = atomicAdd(&col_cnt[e * CSTRIDE], 1);
            if (s < CMAX) col_idx[(size_t)e * CMAX + s] = (unsigned short)n;
        }
        return;
    }

    const int lane = t & 63;
    const int w    = t >> 6;
    const int wm   = (w >> 1) * 64;
    const int wn   = (w & 1) * 64;

    int rt, ct, ostride;
    const float* __restrict__ A;
    const bf16* __restrict__ W;
    const bf16* __restrict__ bias;
    bf16* __restrict__ outp;
    if (blockIdx.x < 512) {
        rt = blockIdx.x >> 3; ct = blockIdx.x & 7;
        A = X0; W = wc + O_MW0; bias = wc + O_MB0; outp = x0cat; ostride = 1024;
    } else {
        const int b = blockIdx.x - 512;
        rt = b >> 2; ct = b & 3;
        A = X1; W = wc + O_MW1; bias = wc + O_MB1; outp = x1cat; ostride = 512;
    }
    const int arow = rt * 128;
    const int tn   = ct * 128;

    f32x4 acc[4][4];
#pragma unroll
    for (int i = 0; i < 4; i++)
#pragma unroll
        for (int j = 0; j < 4; j++)
#pragma unroll
            for (int r = 0; r < 4; r++) acc[i][j][r] = 0.f;

    const int m0 = t >> 2,         q0 = t & 3;
    const int m1 = (t + 256) >> 2, q1 = (t + 256) & 3;
    const int fq = lane >> 4, fr = lane & 15;

    for (int k0 = 0; k0 < 256; k0 += 32) {
        f32x4 a0l = *(const f32x4*)(A + (size_t)(arow + m0) * 256 + k0 + q0 * 8);
        f32x4 a0h = *(const f32x4*)(A + (size_t)(arow + m0) * 256 + k0 + q0 * 8 + 4);
        f32x4 a1l = *(const f32x4*)(A + (size_t)(arow + m1) * 256 + k0 + q1 * 8);
        f32x4 a1h = *(const f32x4*)(A + (size_t)(arow + m1) * 256 + k0 + q1 * 8 + 4);
        union { s16x8 v; bf16 e[8]; } u0, u1;
#pragma unroll
        for (int j = 0; j < 4; j++) {
            u0.e[j] = __float2bfloat16(a0l[j]); u0.e[4 + j] = __float2bfloat16(a0h[j]);
            u1.e[j] = __float2bfloat16(a1l[j]); u1.e[4 + j] = __float2bfloat16(a1h[j]);
        }
        s16x8 sb0 = *(const s16x8*)(W + (size_t)(tn + m0) * 256 + k0 + q0 * 8);
        s16x8 sb1 = *(const s16x8*)(W + (size_t)(tn + m1) * 256 + k0 + q1 * 8);

        __syncthreads();
        *(s16x8*)&As[q0 * QSTRIDE + m0 * 8] = u0.v;
        *(s16x8*)&As[q1 * QSTRIDE + m1 * 8] = u1.v;
        *(s16x8*)&Bs[q0 * QSTRIDE + m0 * 8] = sb0;
        *(s16x8*)&Bs[q1 * QSTRIDE + m1 * 8] = sb1;
        __syncthreads();

        s16x8 af[4], bfv[4];
#pragma unroll
        for (int i = 0; i < 4; i++) {
            af[i]  = *(const s16x8*)&As[fq * QSTRIDE + (wm + i * 16 + fr) * 8];
            bfv[i] = *(const s16x8*)&Bs[fq * QSTRIDE + (wn + i * 16 + fr) * 8];
        }
#pragma unroll
        for (int i = 0; i < 4; i++)
#pragma unroll
            for (int j = 0; j < 4; j++)
                acc[i][j] = __builtin_amdgcn_mfma_f32_16x16x32_bf16(
                    af[i], bfv[j], acc[i][j], 0, 0, 0);
    }

#pragma unroll
    for (int j = 0; j < 4; j++) {
        const int ncol = tn + wn + j * 16 + fr;
        const float bj = __bfloat162float(bias[ncol]);
#pragma unroll
        for (int i = 0; i < 4; i++)
#pragma unroll
            for (int r = 0; r < 4; r++) {
                const int mrow = arow + wm + i * 16 + fq * 4 + r;
                outp[(size_t)mrow * ostride + ncol] = __float2bfloat16(acc[i][j][r] + bj);
            }
    }
}

// ---------------------------------------------------------------------------
// Fused out-proj + residual + LayerNorm (+ optional kv = y@W2^T + bias2).
// NEW vs round 4: both k-loops are software-pipelined with register prefetch
// (next k-step's global loads issue before the MFMA consumes the current
// LDS tile). ln1 runs at 1 block/CU on 32 CUs -> no TLP to hide latency,
// so ILP prefetch is the only lever there. VGPR growth is free at these
// grid sizes (<=1 block/CU anyway).
// ---------------------------------------------------------------------------
__global__ __launch_bounds__(256)
void gemm_ln(const bf16* __restrict__ A, const bf16* __restrict__ W,
             const float* __restrict__ biasF, const bf16* __restrict__ xp, int xps,
             const float* __restrict__ g, const float* __restrict__ b,
             float* __restrict__ outF,
             const bf16* __restrict__ W2, const bf16* __restrict__ bias2,
             bf16* __restrict__ kvout)
{
    __shared__ __align__(16) bf16 As[4 * ASTRIDE];
    __shared__ __align__(16) bf16 Bs[4 * BSTRIDE];
    __shared__ __align__(16) bf16 Ys[32 * YSTRIDE];   // y as [kq][row][8]
    __shared__ float rs1[64], rs2[64];

    const int t    = threadIdx.x;
    const int lane = t & 63;
    const int w    = t >> 6;
    const int fq   = lane >> 4;
    const int fr   = lane & 15;
    const int tm   = blockIdx.x * 64;

    if (t < 64) { rs1[t] = 0.f; rs2[t] = 0.f; }

    f32x4 acc[4][4];
#pragma unroll
    for (int i = 0; i < 4; i++)
#pragma unroll
        for (int j = 0; j < 4; j++)
#pragma unroll
            for (int r = 0; r < 4; r++) acc[i][j][r] = 0.f;

    const int mA = t >> 2, qA = t & 3;

    // prologue: preload k0 = 0
    s16x8 sa = *(const s16x8*)(A + (size_t)(tm + mA) * 256 + qA * 8);
    s16x8 sb[4];
#pragma unroll
    for (int s = 0; s < 4; s++)
        sb[s] = *(const s16x8*)(W + (size_t)(mA + 64 * s) * 256 + qA * 8);

    for (int k0 = 0; k0 < 256; k0 += 32) {
        __syncthreads();
        *(s16x8*)&As[qA * ASTRIDE + mA * 8] = sa;
#pragma unroll
        for (int s = 0; s < 4; s++)
            *(s16x8*)&Bs[qA * BSTRIDE + (mA + 64 * s) * 8] = sb[s];
        __syncthreads();

        // prefetch next k-step (wraps to 0 on last iter: harmless reload)
        const int kn = (k0 + 32) & 255;
        sa = *(const s16x8*)(A + (size_t)(tm + mA) * 256 + kn + qA * 8);
#pragma unroll
        for (int s = 0; s < 4; s++)
            sb[s] = *(const s16x8*)(W + (size_t)(mA + 64 * s) * 256 + kn + qA * 8);

        s16x8 af[4], bfv[4];
#pragma unroll
        for (int i = 0; i < 4; i++) {
            af[i]  = *(const s16x8*)&As[fq * ASTRIDE + (i * 16 + fr) * 8];
            bfv[i] = *(const s16x8*)&Bs[fq * BSTRIDE + (w * 64 + i * 16 + fr) * 8];
        }
#pragma unroll
        for (int i = 0; i < 4; i++)
#pragma unroll
            for (int j = 0; j < 4; j++)
                acc[i][j] = __builtin_amdgcn_mfma_f32_16x16x32_bf16(
                    af[i], bfv[j], acc[i][j], 0, 0, 0);
    }

    float bj[4], gj[4], bbj[4];
    int colv[4];
#pragma unroll
    for (int j = 0; j < 4; j++) {
        colv[j] = w * 64 + j * 16 + fr;
        bj[j]  = biasF[colv[j]];
        gj[j]  = g[colv[j]];
        bbj[j] = b[colv[j]];
    }

#pragma unroll
    for (int i = 0; i < 4; i++) {
#pragma unroll
        for (int r = 0; r < 4; r++) {
            const int row = i * 16 + fq * 4 + r;
            float t1 = 0.f, t2 = 0.f;
#pragma unroll
            for (int j = 0; j < 4; j++) {
                float v = acc[i][j][r] + bj[j]
                        + __bfloat162float(xp[(size_t)(tm + row) * xps + colv[j]]);
                acc[i][j][r] = v;
                t1 += v;
                t2 += v * v;
            }
#pragma unroll
            for (int o = 1; o < 16; o <<= 1) {
                t1 += __shfl_xor(t1, o);
                t2 += __shfl_xor(t2, o);
            }
            if (fr == 0) {
                atomicAdd(&rs1[row], t1);
                atomicAdd(&rs2[row], t2);
            }
        }
    }
    __syncthreads();

#pragma unroll
    for (int i = 0; i < 4; i++) {
#pragma unroll
        for (int r = 0; r < 4; r++) {
            const int row = i * 16 + fq * 4 + r;
            const float mu  = rs1[row] * (1.f / 256.f);
            const float var = rs2[row] * (1.f / 256.f) - mu * mu;
            const float rstd = rsqrtf(var + 1e-5f);
#pragma unroll
            for (int j = 0; j < 4; j++) {
                const float y = (acc[i][j][r] - mu) * rstd * gj[j] + bbj[j];
                outF[(size_t)(tm + row) * 256 + colv[j]] = y;
                if (kvout) {
                    const int c = colv[j];
                    Ys[(c >> 3) * YSTRIDE + row * 8 + (c & 7)] = __float2bfloat16(y);
                }
            }
        }
    }

    if (!kvout) return;

    // ---------------- phase 2: kv = y @ W2^T + bias2 (pipelined) ----------------
    __syncthreads();
    const int wc0 = w * 128;
#pragma unroll
    for (int chunk = 0; chunk < 2; chunk++) {
        const int cbase = wc0 + chunk * 64;
        f32x4 a2[4][4];
#pragma unroll
        for (int i = 0; i < 4; i++)
#pragma unroll
            for (int j = 0; j < 4; j++)
#pragma unroll
                for (int r = 0; r < 4; r++) a2[i][j][r] = 0.f;

        s16x8 bv[4];
#pragma unroll
        for (int j = 0; j < 4; j++)
            bv[j] = *(const s16x8*)(W2 + (size_t)(cbase + j * 16 + fr) * 256 + fq * 8);

        for (int k0 = 0; k0 < 256; k0 += 32) {
            s16x8 af[4];
#pragma unroll
            for (int i = 0; i < 4; i++)
                af[i] = *(const s16x8*)&Ys[(k0 / 8 + fq) * YSTRIDE + (i * 16 + fr) * 8];

            const int kn = (k0 + 32) & 255;
            s16x8 bn[4];
#pragma unroll
            for (int j = 0; j < 4; j++)
                bn[j] = *(const s16x8*)(W2 + (size_t)(cbase + j * 16 + fr) * 256 + kn + fq * 8);

#pragma unroll
            for (int i = 0; i < 4; i++)
#pragma unroll
                for (int j = 0; j < 4; j++)
                    a2[i][j] = __builtin_amdgcn_mfma_f32_16x16x32_bf16(
                        af[i], bv[j], a2[i][j], 0, 0, 0);
#pragma unroll
            for (int j = 0; j < 4; j++) bv[j] = bn[j];
        }

#pragma unroll
        for (int j = 0; j < 4; j++) {
            const int col = cbase + j * 16 + fr;
            const float bb = __bfloat162float(bias2[col]);
#pragma unroll
            for (int i = 0; i < 4; i++)
#pragma unroll
                for (int r = 0; r < 4; r++) {
                    const int row = i * 16 + fq * 4 + r;
                    kvout[(size_t)(tm + row) * 512 + col] = __float2bfloat16(a2[i][j][r] + bb);
                }
        }
    }
}

// ---------------------------------------------------------------------------
// Sparse masked attention. NEW vs round 4: cooperative neighbor-list load
// (all 4 waves) and unroll 4 on both gather loops (4 gathers in flight per
// lane chain instead of 2 -> halves exposed L2/L3 latency).
// ---------------------------------------------------------------------------
__global__ __launch_bounds__(256)
void sparse_attn(const bf16* __restrict__ Q, int qs,
                 const bf16* __restrict__ Kb, const bf16* __restrict__ Vb, int kvs,
                 const int* __restrict__ cnts, int cstride,
                 const unsigned short* __restrict__ idx,
                 int lmax, int idxmask, bf16* __restrict__ out)
{
    __shared__ float sc[4][CMAX];
    __shared__ unsigned short nls[CMAX];
    const int qi   = blockIdx.x;
    const int h    = threadIdx.x >> 6;
    const int lane = threadIdx.x & 63;
    const int grp  = lane >> 3;
    const int sub  = lane & 7;

    int n = cnts[(size_t)qi * cstride];
    if (n > lmax) n = lmax;

    for (int i = threadIdx.x; i < n; i += 256)
        nls[i] = (unsigned short)(((int)idx[(size_t)qi * lmax + i]) & idxmask);
    __syncthreads();

    if (n <= 0) {
        out[(size_t)qi * 256 + h * 64 + lane] = __float2bfloat16(0.f);
        return;
    }

    float qv[8];
    {
        union { f32x4 v; unsigned short u[8]; } qu;
        qu.v = *(const f32x4*)(Q + (size_t)qi * qs + h * 64 + sub * 8);
#pragma unroll
        for (int j = 0; j < 8; j++)
            qv[j] = __uint_as_float(((unsigned)qu.u[j]) << 16) * 0.125f;
    }

    float mx = -1e30f;
#pragma unroll 4
    for (int base = 0; base < n; base += 8) {
        const int i = base + grp;
        float s = -1e30f;
        if (i < n) {
            const int nb = nls[i];
            union { f32x4 v; unsigned short u[8]; } ku;
            ku.v = *(const f32x4*)(Kb + (size_t)nb * kvs + h * 64 + sub * 8);
            float a = 0.f;
#pragma unroll
            for (int j = 0; j < 8; j++)
                a += __uint_as_float(((unsigned)ku.u[j]) << 16) * qv[j];
            a += __shfl_xor(a, 1);
            a += __shfl_xor(a, 2);
            a += __shfl_xor(a, 4);
            if (sub == 0) sc[h][i] = a;
            s = a;
        }
        mx = fmaxf(mx, s);
    }
#pragma unroll
    for (int o = 32; o > 0; o >>= 1) mx = fmaxf(mx, __shfl_xor(mx, o));

    float sum = 0.f;
    for (int base = 0; base < n; base += 64) {
        const int i = base + lane;
        if (i < n) {
            const float p = __expf(sc[h][i] - mx);
            sc[h][i] = p;
            sum += p;
        }
    }
#pragma unroll
    for (int o = 32; o > 0; o >>= 1) sum += __shfl_xor(sum, o);
    const float inv = 1.f / sum;

    float oa[8];
#pragma unroll
    for (int j = 0; j < 8; j++) oa[j] = 0.f;
#pragma unroll 4
    for (int base = 0; base < n; base += 8) {
        const int i = base + grp;
        if (i < n) {
            const float p = sc[h][i];
            const int nb = nls[i];
            union { f32x4 v; unsigned short u[8]; } vu;
            vu.v = *(const f32x4*)(Vb + (size_t)nb * kvs + h * 64 + sub * 8);
#pragma unroll
            for (int j = 0; j < 8; j++)
                oa[j] += p * __uint_as_float(((unsigned)vu.u[j]) << 16);
        }
    }
#pragma unroll
    for (int j = 0; j < 8; j++) {
        oa[j] += __shfl_xor(oa[j], 8);
        oa[j] += __shfl_xor(oa[j], 16);
        oa[j] += __shfl_xor(oa[j], 32);
    }
    if (grp == 0) {
        union { s16x8 v; bf16 e[8]; } ou;
#pragma unroll
        for (int j = 0; j < 8; j++) ou.e[j] = __float2bfloat16(oa[j] * inv);
        *(s16x8*)(out + (size_t)qi * 256 + h * 64 + sub * 8) = ou.v;
    }
}

// ---------------------------------------------------------------------------
extern "C" void kernel_launch(void* const* d_in, const int* in_sizes, int n_in,
                              void* d_out, int out_size, void* d_ws, size_t ws_size,
                              hipStream_t stream)
{
    const int N = 8192, E = 2048;

    float* out0 = (float*)d_out;
    float* out1 = (float*)d_out + (size_t)N * 256;

    char* wp = (char*)d_ws;
    auto carve = [&](size_t bytes) { void* p = wp; wp += (bytes + 15) & ~size_t(15); return p; };

    bf16*  wcat    = (bf16*)          carve(657408 * 2);
    int*   col_cnt = (int*)           carve((size_t)E * CSTRIDE * 4);
    int*   row_cnt = (int*)           carve((size_t)N * 4);
    unsigned short* col_idx = (unsigned short*)carve((size_t)E * CMAX * 2);
    unsigned short* row_idx = (unsigned short*)carve((size_t)N * RMAX * 2);
    bf16*  x0cat   = (bf16*) carve((size_t)N * 1024 * 2);
    bf16*  x1cat   = (bf16*) carve((size_t)E * 512 * 2);
    bf16*  attn1   = (bf16*) carve((size_t)E * 256 * 2);
    bf16*  kv2     = (bf16*) carve((size_t)E * 512 * 2);
    bf16*  attn2   = (bf16*) carve((size_t)N * 256 * 2);

    const float* nw = (const float*)d_in[3];
    const float* nb = (const float*)d_in[4];
    const float* ew = (const float*)d_in[5];
    const float* eb = (const float*)d_in[6];
    const float* w1 = (const float*)d_in[7];
    const float* b1 = (const float*)d_in[8];
    const float* w2 = (const float*)d_in[11];
    const float* b2 = (const float*)d_in[12];

    PrepDesc pd;
    pd.aw[0] = w1 + 65536;  pd.pw[0] = nw; pd.ab[0] = b1 + 256; pd.pb[0] = nb;
    pd.cdst[0] = O_MW0 + 65536;  pd.bdst[0] = O_MB0 + 256;   // k1
    pd.aw[1] = w1 + 131072; pd.pw[1] = nw; pd.ab[1] = b1 + 512; pd.pb[1] = nb;
    pd.cdst[1] = O_MW0 + 131072; pd.bdst[1] = O_MB0 + 512;   // v1
    pd.aw[2] = w2;          pd.pw[2] = nw; pd.ab[2] = b2;      pd.pb[2] = nb;
    pd.cdst[2] = O_MW0 + 196608; pd.bdst[2] = O_MB0 + 768;   // q2
    pd.aw[3] = w1;          pd.pw[3] = ew; pd.ab[3] = b1;      pd.pb[3] = eb;
    pd.cdst[3] = O_MW1 + 65536;  pd.bdst[3] = O_MB1 + 256;   // q1
    const float* csrc[8] = { nw, ew, w2 + 65536, (const float*)d_in[9],
                             (const float*)d_in[13], nb, eb, b2 + 256 };
    const int coff[8] = {O_MW0, O_MW1, O_KV2W, O_O1W, O_O2W, O_MB0, O_MB1, O_KV2B};
    const int ccnt[8] = {65536, 65536, 131072, 65536, 65536, 256, 256, 512};
    for (int i = 0; i < 8; i++) { pd.csrc[i] = csrc[i]; pd.coff[i] = coff[i]; pd.ccnt[i] = ccnt[i]; }

    // 1. fused front: weight prep (256 blocks) + row lists / col_cnt zero (2048)
    prep_front<<<256 + 2048, 256, 0, stream>>>(pd, wcat, (const float*)d_in[2],
                                               col_cnt, row_cnt, row_idx);

    // 2. mega GEMM (x0cat 512 blocks, x1cat 64) + col lists (256)
    gemm_mega<<<576 + 256, 256, 0, stream>>>((const float*)d_in[0],
                                             (const float*)d_in[1], wcat,
                                             x0cat, x1cat,
                                             row_cnt, row_idx, col_cnt, col_idx);

    // ---- stage 1: node -> edge ----
    sparse_attn<<<E, 256, 0, stream>>>(x1cat + 256, 512,
                                       x0cat + 256, x0cat + 512, 1024,
                                       col_cnt, CSTRIDE, col_idx, CMAX, N - 1, attn1);
    gemm_ln<<<E / 64, 256, 0, stream>>>(attn1, wcat + O_O1W, (const float*)d_in[10],
                                        x1cat, 512,
                                        (const float*)d_in[15], (const float*)d_in[16],
                                        out1,
                                        wcat + O_KV2W, wcat + O_KV2B, kv2);

    // ---- stage 2: edge -> node ----
    sparse_attn<<<N, 256, 0, stream>>>(x0cat + 768, 1024, kv2, kv2 + 256, 512,
                                       row_cnt, 1, row_idx, RMAX, E - 1, attn2);
    gemm_ln<<<N / 64, 256, 0, stream>>>(attn2, wcat + O_O2W, (const float*)d_in[14],
                                        x0cat, 1024,
                                        (const float*)d_in[17], (const float*)d_in[18],
                                        out0,
                                        nullptr, nullptr, nullptr);
}